// Round 6
// baseline (268.884 us; speedup 1.0000x reference)
//
#include <hip/hip_runtime.h>
#include <math.h>

// SoftPeakAwareLoss on MI355X — R5: in-core-bound fix.
// R3 evidence: L3-warm replays (FETCH 61KB) run at the SAME 105us as cold
// (143MB) -> kernel is NOT memory-bound; it's dep-chain/issue bound
// (VALUBusy 28%). R5: 2 independent days per thread in one straight-line
// body (ILP x2), tournament argmax (depth 4), max3-fusable max trees,
// fma-folded exp, v_rcp instead of full divides. Lane pair (even/odd)
// splits each day's 24h; shfl_xor(1) butterflies combine.

#define HOURS_ 24
#define WIN_ 2
#define NEGV (-1e9f)

__device__ __forceinline__ float frcp(float x) { return __builtin_amdgcn_rcpf(x); }

__device__ __forceinline__ void day_body(
    float4 pa0, float4 pa1, float4 pa2,
    float4 ta0, float4 ta1, float4 ta2,
    float4 da0, float4 da1, float4 da2,
    int h0g, int half,
    float& o, float& mg, float& tl, float& sh)
{
    float a[12] = {pa0.x, pa0.y, pa0.z, pa0.w, pa1.x, pa1.y, pa1.z, pa1.w,
                   pa2.x, pa2.y, pa2.z, pa2.w};
    float b[12] = {ta0.x, ta0.y, ta0.z, ta0.w, ta1.x, ta1.y, ta1.z, ta1.w,
                   ta2.x, ta2.y, ta2.z, ta2.w};
    float dv[12] = {da0.x, da0.y, da0.z, da0.w, da1.x, da1.y, da1.z, da1.w,
                    da2.x, da2.y, da2.z, da2.w};
    float bm[12], am[12];
    #pragma unroll
    for (int k = 0; k < 12; ++k) {
        bool dy = dv[k] > 0.5f;
        bm[k] = dy ? b[k] : NEGV;
        am[k] = dy ? a[k] : NEGV;
    }

    // ---- L_overall partial
    #pragma unroll
    for (int k = 0; k < 12; ++k) { float d = a[k] - b[k]; o = fmaf(d, d, o); }

    // ---- tournament argmax on bm (first occurrence: strict >, ordered tree)
    float tv_[6]; int ti_[6];
    #pragma unroll
    for (int k = 0; k < 6; ++k) {            // 12 -> 6
        bool t = bm[2*k+1] > bm[2*k];
        tv_[k] = t ? bm[2*k+1] : bm[2*k];
        ti_[k] = t ? (h0g + 2*k+1) : (h0g + 2*k);
    }
    #pragma unroll
    for (int k = 0; k < 3; ++k) {            // 6 -> 3
        bool t = tv_[2*k+1] > tv_[2*k];
        tv_[k] = t ? tv_[2*k+1] : tv_[2*k];
        ti_[k] = t ? ti_[2*k+1] : ti_[2*k];
    }
    bool t01 = tv_[1] > tv_[0];
    float fv = t01 ? tv_[1] : tv_[0];
    int   fi = t01 ? ti_[1] : ti_[0];
    bool t2  = tv_[2] > fv;
    float mt = t2 ? tv_[2] : fv;
    int   pk = t2 ? ti_[2] : fi;

    // ---- mp: max of masked pred (max3-fusable triples)
    float mpa = fmaxf(fmaxf(am[0], am[1]), am[2]);
    float mpb = fmaxf(fmaxf(am[3], am[4]), am[5]);
    float mpc = fmaxf(fmaxf(am[6], am[7]), am[8]);
    float mpd = fmaxf(fmaxf(am[9], am[10]), am[11]);
    float mp  = fmaxf(fmaxf(mpa, mpb), fmaxf(mpc, mpd));

    // ---- butterfly combine with partner lane (ties -> lower hour)
    {
        float mt_o = __shfl_xor(mt, 1);
        int   pk_o = __shfl_xor(pk, 1);
        float mp_o = __shfl_xor(mp, 1);
        bool takeo = (mt_o > mt) || (mt_o == mt && pk_o < pk);
        pk = takeo ? pk_o : pk;
        mt = fmaxf(mt, mt_o);
        mp = fmaxf(mp, mp_o);
    }

    // ---- soft peaks: exp((x - m) * 10) via fma fold; night -> exp(-1e10)=0
    float mt10 = mt * 10.f, mp10 = mp * 10.f;
    float set = 0.f, syt = 0.f, sht = 0.f;
    float sep = 0.f, syp = 0.f, shp = 0.f;
    #pragma unroll
    for (int k = 0; k < 12; ++k) {
        float et = __expf(fmaf(bm[k], 10.f, -mt10));
        float ep = __expf(fmaf(am[k], 10.f, -mp10));
        float hh = (float)(h0g + k);
        set += et; syt = fmaf(et, b[k], syt); sht = fmaf(et, hh, sht);
        sep += ep; syp = fmaf(ep, a[k], syp); shp = fmaf(ep, hh, shp);
    }
    set += __shfl_xor(set, 1); syt += __shfl_xor(syt, 1); sht += __shfl_xor(sht, 1);
    sep += __shfl_xor(sep, 1); syp += __shfl_xor(syp, 1); shp += __shfl_xor(shp, 1);
    {
        float rs = frcp(set), rq = frcp(sep);
        float tvv = syt * rs, ttv = sht * rs;
        float pvv = syp * rq, ptv = shp * rq;
        float d1 = pvv - tvv, d2 = ptv - ttv;
        float dmg = d1 * d1, dtl = d2 * d2;
        mg += half ? 0.f : dmg;      // count once per day
        tl += half ? 0.f : dtl;
    }

    // ---- shape loss: window [pk-2, pk+2] clipped; analytic 1/cnt (exact)
    int lo = pk - WIN_; lo = lo < 0 ? 0 : lo;
    int hi = pk + WIN_; hi = hi > 23 ? 23 : hi;
    int cnt = hi - lo + 1;                        // 3,4,5
    float invcnt = (cnt == 5) ? 0.2f : ((cnt == 4) ? 0.25f : (1.f / 3.f));
    float twm = -INFINITY, pwm = -INFINITY;
    #pragma unroll
    for (int k = 0; k < 12; ++k) {
        int hg = h0g + k;
        bool in = (hg >= lo) && (hg <= hi);
        twm = in ? fmaxf(twm, b[k]) : twm;
        pwm = in ? fmaxf(pwm, a[k]) : pwm;
    }
    twm = fmaxf(twm, __shfl_xor(twm, 1));
    pwm = fmaxf(pwm, __shfl_xor(pwm, 1));
    {
        float rt  = frcp(twm + 1e-6f);
        float rpw = frcp(pwm + 1e-6f);
        float ss = 0.f;
        #pragma unroll
        for (int k = 0; k < 12; ++k) {
            int hg = h0g + k;
            bool in = (hg >= lo) && (hg <= hi);
            float d = fmaf(a[k], rpw, -(b[k] * rt));
            ss = in ? fmaf(d, d, ss) : ss;
        }
        sh = fmaf(ss, invcnt, sh);    // (ssA+ssB)*invcnt sums across the pair
    }
}

__global__ __launch_bounds__(256) void splloss_days(
    const float* __restrict__ ypred,
    const float* __restrict__ ytrue,
    const float* __restrict__ isday,
    float4* __restrict__ partials,
    int n_days)
{
    const int tid  = threadIdx.x;
    const int half = tid & 1;
    const int h0g  = half * 12;
    const int pair = blockIdx.x * 128 + (tid >> 1);
    const int strideDays = gridDim.x * 128;

    const int day0 = pair;
    const int day1 = pair + strideDays;
    const bool v0 = day0 < n_days;
    const bool v1 = day1 < n_days;
    const int d0 = v0 ? day0 : 0;
    const int d1 = v1 ? day1 : 0;

    // ---- issue all 18 loads up front (two independent days)
    const float4* A0 = reinterpret_cast<const float4*>(ypred + (size_t)d0 * 24 + h0g);
    const float4* B0 = reinterpret_cast<const float4*>(ytrue + (size_t)d0 * 24 + h0g);
    const float4* D0 = reinterpret_cast<const float4*>(isday + (size_t)d0 * 24 + h0g);
    const float4* A1 = reinterpret_cast<const float4*>(ypred + (size_t)d1 * 24 + h0g);
    const float4* B1 = reinterpret_cast<const float4*>(ytrue + (size_t)d1 * 24 + h0g);
    const float4* D1 = reinterpret_cast<const float4*>(isday + (size_t)d1 * 24 + h0g);
    float4 pa0 = A0[0], pa1 = A0[1], pa2 = A0[2];
    float4 ta0 = B0[0], ta1 = B0[1], ta2 = B0[2];
    float4 da0 = D0[0], da1 = D0[1], da2 = D0[2];
    float4 qa0 = A1[0], qa1 = A1[1], qa2 = A1[2];
    float4 ua0 = B1[0], ua1 = B1[1], ua2 = B1[2];
    float4 ea0 = D1[0], ea1 = D1[1], ea2 = D1[2];

    // ---- two independent straight-line day bodies (scheduler interleaves)
    float o0 = 0.f, mg0 = 0.f, tl0 = 0.f, sh0 = 0.f;
    float o1 = 0.f, mg1 = 0.f, tl1 = 0.f, sh1 = 0.f;
    day_body(pa0, pa1, pa2, ta0, ta1, ta2, da0, da1, da2, h0g, half, o0, mg0, tl0, sh0);
    day_body(qa0, qa1, qa2, ua0, ua1, ua2, ea0, ea1, ea2, h0g, half, o1, mg1, tl1, sh1);

    float o  = (v0 ? o0  : 0.f) + (v1 ? o1  : 0.f);
    float mg = (v0 ? mg0 : 0.f) + (v1 ? mg1 : 0.f);
    float tl = (v0 ? tl0 : 0.f) + (v1 ? tl1 : 0.f);
    float sh = (v0 ? sh0 : 0.f) + (v1 ? sh1 : 0.f);

    // ---- block reduction: wave shuffle then LDS across the 4 waves
    #pragma unroll
    for (int off = 32; off > 0; off >>= 1) {
        o  += __shfl_down(o,  off);
        mg += __shfl_down(mg, off);
        tl += __shfl_down(tl, off);
        sh += __shfl_down(sh, off);
    }
    __shared__ float4 red[4];
    int wid = threadIdx.x >> 6;
    if ((threadIdx.x & 63) == 0) red[wid] = make_float4(o, mg, tl, sh);
    __syncthreads();
    if (threadIdx.x == 0) {
        float4 r0 = red[0], r1 = red[1], r2 = red[2], r3 = red[3];
        partials[blockIdx.x] = make_float4(r0.x + r1.x + r2.x + r3.x,
                                           r0.y + r1.y + r2.y + r3.y,
                                           r0.z + r1.z + r2.z + r3.z,
                                           r0.w + r1.w + r2.w + r3.w);
    }
}

__global__ __launch_bounds__(256) void splloss_final(
    const float4* __restrict__ partials, int nb, float* __restrict__ out,
    double inv_bs, double inv_bd, double inv_shape)
{
    double o = 0.0, m = 0.0, t = 0.0, s = 0.0;
    for (int i = threadIdx.x; i < nb; i += 256) {
        float4 p = partials[i];
        o += (double)p.x; m += (double)p.y; t += (double)p.z; s += (double)p.w;
    }
    #pragma unroll
    for (int off = 32; off > 0; off >>= 1) {
        o += __shfl_down(o, off);
        m += __shfl_down(m, off);
        t += __shfl_down(t, off);
        s += __shfl_down(s, off);
    }
    __shared__ double red[4][4];
    int wid = threadIdx.x >> 6;
    if ((threadIdx.x & 63) == 0) { red[wid][0] = o; red[wid][1] = m; red[wid][2] = t; red[wid][3] = s; }
    __syncthreads();
    if (threadIdx.x == 0) {
        double ot = red[0][0] + red[1][0] + red[2][0] + red[3][0];
        double mt = red[0][1] + red[1][1] + red[2][1] + red[3][1];
        double tt = red[0][2] + red[1][2] + red[2][2] + red[3][2];
        double st = red[0][3] + red[1][3] + red[2][3] + red[3][3];
        double total = 1.0 * (ot * inv_bs)
                     + 2.0 * (mt * inv_bd)
                     + 1.0 * (tt * inv_bd)
                     + 0.5 * (st * inv_shape);
        out[0] = (float)total;
    }
}

extern "C" void kernel_launch(void* const* d_in, const int* in_sizes, int n_in,
                              void* d_out, int out_size, void* d_ws, size_t ws_size,
                              hipStream_t stream) {
    const float* yp = (const float*)d_in[0];
    const float* yt = (const float*)d_in[1];
    const float* dm = (const float*)d_in[2];
    float* out = (float*)d_out;

    int n = in_sizes[0];              // B*S; S divisible by 24
    int n_days = n / HOURS_;          // B*D

    // 256 days per block (128 pairs x 2 days each, straight-line)
    int nb = (n_days + 255) / 256;    // 3840 at the bench shape

    float4* partials = (float4*)d_ws; // nb * 16 bytes

    splloss_days<<<nb, 256, 0, stream>>>(yp, yt, dm, partials, n_days);

    double inv_bs    = 1.0 / (double)n;
    double inv_bd    = 1.0 / (double)n_days;
    double inv_shape = 1.0 / ((double)n_days + 1e-6);
    splloss_final<<<1, 256, 0, stream>>>(partials, nb, out, inv_bs, inv_bd, inv_shape);
}

// Round 7
// 267.311 us; speedup vs baseline: 1.0059x; 1.0059x over previous
//
#include <hip/hip_runtime.h>
#include <math.h>

// SoftPeakAwareLoss on MI355X — R6: break the compiler's VGPR starvation.
// R0/R1/R3/R5 all ~105-117us with VGPR 60-68: the compiler's default
// occupancy target (8 waves/SIMD -> <=64 VGPR) cannot hold 18 float4 load
// destinations (72 VGPRs), so it serializes loads into load->waitcnt->
// consume->reuse rounds; MLP collapses and BW pins at ~1.4 TB/s.
// Single change vs R5: __launch_bounds__(256, 4) -> 128-VGPR budget,
// all 18 loads of both days issue before the first consume.

#define HOURS_ 24
#define WIN_ 2
#define NEGV (-1e9f)

__device__ __forceinline__ float frcp(float x) { return __builtin_amdgcn_rcpf(x); }

__device__ __forceinline__ void day_body(
    float4 pa0, float4 pa1, float4 pa2,
    float4 ta0, float4 ta1, float4 ta2,
    float4 da0, float4 da1, float4 da2,
    int h0g, int half,
    float& o, float& mg, float& tl, float& sh)
{
    float a[12] = {pa0.x, pa0.y, pa0.z, pa0.w, pa1.x, pa1.y, pa1.z, pa1.w,
                   pa2.x, pa2.y, pa2.z, pa2.w};
    float b[12] = {ta0.x, ta0.y, ta0.z, ta0.w, ta1.x, ta1.y, ta1.z, ta1.w,
                   ta2.x, ta2.y, ta2.z, ta2.w};
    float dv[12] = {da0.x, da0.y, da0.z, da0.w, da1.x, da1.y, da1.z, da1.w,
                    da2.x, da2.y, da2.z, da2.w};
    float bm[12], am[12];
    #pragma unroll
    for (int k = 0; k < 12; ++k) {
        bool dy = dv[k] > 0.5f;
        bm[k] = dy ? b[k] : NEGV;
        am[k] = dy ? a[k] : NEGV;
    }

    // ---- L_overall partial
    #pragma unroll
    for (int k = 0; k < 12; ++k) { float d = a[k] - b[k]; o = fmaf(d, d, o); }

    // ---- tournament argmax on bm (first occurrence: strict >, ordered tree)
    float tv_[6]; int ti_[6];
    #pragma unroll
    for (int k = 0; k < 6; ++k) {            // 12 -> 6
        bool t = bm[2*k+1] > bm[2*k];
        tv_[k] = t ? bm[2*k+1] : bm[2*k];
        ti_[k] = t ? (h0g + 2*k+1) : (h0g + 2*k);
    }
    #pragma unroll
    for (int k = 0; k < 3; ++k) {            // 6 -> 3
        bool t = tv_[2*k+1] > tv_[2*k];
        tv_[k] = t ? tv_[2*k+1] : tv_[2*k];
        ti_[k] = t ? ti_[2*k+1] : ti_[2*k];
    }
    bool t01 = tv_[1] > tv_[0];
    float fv = t01 ? tv_[1] : tv_[0];
    int   fi = t01 ? ti_[1] : ti_[0];
    bool t2  = tv_[2] > fv;
    float mt = t2 ? tv_[2] : fv;
    int   pk = t2 ? ti_[2] : fi;

    // ---- mp: max of masked pred (max3-fusable triples)
    float mpa = fmaxf(fmaxf(am[0], am[1]), am[2]);
    float mpb = fmaxf(fmaxf(am[3], am[4]), am[5]);
    float mpc = fmaxf(fmaxf(am[6], am[7]), am[8]);
    float mpd = fmaxf(fmaxf(am[9], am[10]), am[11]);
    float mp  = fmaxf(fmaxf(mpa, mpb), fmaxf(mpc, mpd));

    // ---- butterfly combine with partner lane (ties -> lower hour)
    {
        float mt_o = __shfl_xor(mt, 1);
        int   pk_o = __shfl_xor(pk, 1);
        float mp_o = __shfl_xor(mp, 1);
        bool takeo = (mt_o > mt) || (mt_o == mt && pk_o < pk);
        pk = takeo ? pk_o : pk;
        mt = fmaxf(mt, mt_o);
        mp = fmaxf(mp, mp_o);
    }

    // ---- soft peaks: exp((x - m) * 10) via fma fold; night -> exp(-1e10)=0
    float mt10 = mt * 10.f, mp10 = mp * 10.f;
    float set = 0.f, syt = 0.f, sht = 0.f;
    float sep = 0.f, syp = 0.f, shp = 0.f;
    #pragma unroll
    for (int k = 0; k < 12; ++k) {
        float et = __expf(fmaf(bm[k], 10.f, -mt10));
        float ep = __expf(fmaf(am[k], 10.f, -mp10));
        float hh = (float)(h0g + k);
        set += et; syt = fmaf(et, b[k], syt); sht = fmaf(et, hh, sht);
        sep += ep; syp = fmaf(ep, a[k], syp); shp = fmaf(ep, hh, shp);
    }
    set += __shfl_xor(set, 1); syt += __shfl_xor(syt, 1); sht += __shfl_xor(sht, 1);
    sep += __shfl_xor(sep, 1); syp += __shfl_xor(syp, 1); shp += __shfl_xor(shp, 1);
    {
        float rs = frcp(set), rq = frcp(sep);
        float tvv = syt * rs, ttv = sht * rs;
        float pvv = syp * rq, ptv = shp * rq;
        float d1 = pvv - tvv, d2 = ptv - ttv;
        float dmg = d1 * d1, dtl = d2 * d2;
        mg += half ? 0.f : dmg;      // count once per day
        tl += half ? 0.f : dtl;
    }

    // ---- shape loss: window [pk-2, pk+2] clipped; analytic 1/cnt (exact)
    int lo = pk - WIN_; lo = lo < 0 ? 0 : lo;
    int hi = pk + WIN_; hi = hi > 23 ? 23 : hi;
    int cnt = hi - lo + 1;                        // 3,4,5
    float invcnt = (cnt == 5) ? 0.2f : ((cnt == 4) ? 0.25f : (1.f / 3.f));
    float twm = -INFINITY, pwm = -INFINITY;
    #pragma unroll
    for (int k = 0; k < 12; ++k) {
        int hg = h0g + k;
        bool in = (hg >= lo) && (hg <= hi);
        twm = in ? fmaxf(twm, b[k]) : twm;
        pwm = in ? fmaxf(pwm, a[k]) : pwm;
    }
    twm = fmaxf(twm, __shfl_xor(twm, 1));
    pwm = fmaxf(pwm, __shfl_xor(pwm, 1));
    {
        float rt  = frcp(twm + 1e-6f);
        float rpw = frcp(pwm + 1e-6f);
        float ss = 0.f;
        #pragma unroll
        for (int k = 0; k < 12; ++k) {
            int hg = h0g + k;
            bool in = (hg >= lo) && (hg <= hi);
            float d = fmaf(a[k], rpw, -(b[k] * rt));
            ss = in ? fmaf(d, d, ss) : ss;
        }
        sh = fmaf(ss, invcnt, sh);    // (ssA+ssB)*invcnt sums across the pair
    }
}

__global__ __launch_bounds__(256, 4) void splloss_days(
    const float* __restrict__ ypred,
    const float* __restrict__ ytrue,
    const float* __restrict__ isday,
    float4* __restrict__ partials,
    int n_days)
{
    const int tid  = threadIdx.x;
    const int half = tid & 1;
    const int h0g  = half * 12;
    const int pair = blockIdx.x * 128 + (tid >> 1);
    const int strideDays = gridDim.x * 128;

    const int day0 = pair;
    const int day1 = pair + strideDays;
    const bool v0 = day0 < n_days;
    const bool v1 = day1 < n_days;
    const int d0 = v0 ? day0 : 0;
    const int d1 = v1 ? day1 : 0;

    // ---- issue all 18 loads up front (two independent days); with the
    // 128-VGPR budget all destinations stay live -> full MLP
    const float4* A0 = reinterpret_cast<const float4*>(ypred + (size_t)d0 * 24 + h0g);
    const float4* B0 = reinterpret_cast<const float4*>(ytrue + (size_t)d0 * 24 + h0g);
    const float4* D0 = reinterpret_cast<const float4*>(isday + (size_t)d0 * 24 + h0g);
    const float4* A1 = reinterpret_cast<const float4*>(ypred + (size_t)d1 * 24 + h0g);
    const float4* B1 = reinterpret_cast<const float4*>(ytrue + (size_t)d1 * 24 + h0g);
    const float4* D1 = reinterpret_cast<const float4*>(isday + (size_t)d1 * 24 + h0g);
    float4 pa0 = A0[0], pa1 = A0[1], pa2 = A0[2];
    float4 ta0 = B0[0], ta1 = B0[1], ta2 = B0[2];
    float4 da0 = D0[0], da1 = D0[1], da2 = D0[2];
    float4 qa0 = A1[0], qa1 = A1[1], qa2 = A1[2];
    float4 ua0 = B1[0], ua1 = B1[1], ua2 = B1[2];
    float4 ea0 = D1[0], ea1 = D1[1], ea2 = D1[2];

    // ---- two independent straight-line day bodies (scheduler interleaves)
    float o0 = 0.f, mg0 = 0.f, tl0 = 0.f, sh0 = 0.f;
    float o1 = 0.f, mg1 = 0.f, tl1 = 0.f, sh1 = 0.f;
    day_body(pa0, pa1, pa2, ta0, ta1, ta2, da0, da1, da2, h0g, half, o0, mg0, tl0, sh0);
    day_body(qa0, qa1, qa2, ua0, ua1, ua2, ea0, ea1, ea2, h0g, half, o1, mg1, tl1, sh1);

    float o  = (v0 ? o0  : 0.f) + (v1 ? o1  : 0.f);
    float mg = (v0 ? mg0 : 0.f) + (v1 ? mg1 : 0.f);
    float tl = (v0 ? tl0 : 0.f) + (v1 ? tl1 : 0.f);
    float sh = (v0 ? sh0 : 0.f) + (v1 ? sh1 : 0.f);

    // ---- block reduction: wave shuffle then LDS across the 4 waves
    #pragma unroll
    for (int off = 32; off > 0; off >>= 1) {
        o  += __shfl_down(o,  off);
        mg += __shfl_down(mg, off);
        tl += __shfl_down(tl, off);
        sh += __shfl_down(sh, off);
    }
    __shared__ float4 red[4];
    int wid = threadIdx.x >> 6;
    if ((threadIdx.x & 63) == 0) red[wid] = make_float4(o, mg, tl, sh);
    __syncthreads();
    if (threadIdx.x == 0) {
        float4 r0 = red[0], r1 = red[1], r2 = red[2], r3 = red[3];
        partials[blockIdx.x] = make_float4(r0.x + r1.x + r2.x + r3.x,
                                           r0.y + r1.y + r2.y + r3.y,
                                           r0.z + r1.z + r2.z + r3.z,
                                           r0.w + r1.w + r2.w + r3.w);
    }
}

__global__ __launch_bounds__(256) void splloss_final(
    const float4* __restrict__ partials, int nb, float* __restrict__ out,
    double inv_bs, double inv_bd, double inv_shape)
{
    double o = 0.0, m = 0.0, t = 0.0, s = 0.0;
    for (int i = threadIdx.x; i < nb; i += 256) {
        float4 p = partials[i];
        o += (double)p.x; m += (double)p.y; t += (double)p.z; s += (double)p.w;
    }
    #pragma unroll
    for (int off = 32; off > 0; off >>= 1) {
        o += __shfl_down(o, off);
        m += __shfl_down(m, off);
        t += __shfl_down(t, off);
        s += __shfl_down(s, off);
    }
    __shared__ double red[4][4];
    int wid = threadIdx.x >> 6;
    if ((threadIdx.x & 63) == 0) { red[wid][0] = o; red[wid][1] = m; red[wid][2] = t; red[wid][3] = s; }
    __syncthreads();
    if (threadIdx.x == 0) {
        double ot = red[0][0] + red[1][0] + red[2][0] + red[3][0];
        double mt = red[0][1] + red[1][1] + red[2][1] + red[3][1];
        double tt = red[0][2] + red[1][2] + red[2][2] + red[3][2];
        double st = red[0][3] + red[1][3] + red[2][3] + red[3][3];
        double total = 1.0 * (ot * inv_bs)
                     + 2.0 * (mt * inv_bd)
                     + 1.0 * (tt * inv_bd)
                     + 0.5 * (st * inv_shape);
        out[0] = (float)total;
    }
}

extern "C" void kernel_launch(void* const* d_in, const int* in_sizes, int n_in,
                              void* d_out, int out_size, void* d_ws, size_t ws_size,
                              hipStream_t stream) {
    const float* yp = (const float*)d_in[0];
    const float* yt = (const float*)d_in[1];
    const float* dm = (const float*)d_in[2];
    float* out = (float*)d_out;

    int n = in_sizes[0];              // B*S; S divisible by 24
    int n_days = n / HOURS_;          // B*D

    // 256 days per block (128 pairs x 2 days each, straight-line)
    int nb = (n_days + 255) / 256;    // 3840 at the bench shape

    float4* partials = (float4*)d_ws; // nb * 16 bytes

    splloss_days<<<nb, 256, 0, stream>>>(yp, yt, dm, partials, n_days);

    double inv_bs    = 1.0 / (double)n;
    double inv_bd    = 1.0 / (double)n_days;
    double inv_shape = 1.0 / ((double)n_days + 1e-6);
    splloss_final<<<1, 256, 0, stream>>>(partials, nb, out, inv_bs, inv_bd, inv_shape);
}